// Round 5
// baseline (158.000 us; speedup 1.0000x reference)
//
#include <hip/hip_runtime.h>

#define NN 8192
#define TT 1024
#define WW 64
#define HH 256
#define NPB 8
#define DTF (1.0f/24.0f)

__device__ __forceinline__ float sigmoidf_(float v) { return 1.0f / (1.0f + __expf(-v)); }

// ---------------- MLP -> (k, xw) -> IRF[n][64] in ws ----------------
__global__ __launch_bounds__(256) void mlp_kernel(
    const float* __restrict__ phys,
    const float* __restrict__ w1, const float* __restrict__ b1,
    const float* __restrict__ w2, const float* __restrict__ b2,
    const float* __restrict__ w3, const float* __restrict__ b3,
    float* __restrict__ irf)
{
    const int n0 = blockIdx.x * NPB;
    const int j  = threadIdx.x;

    __shared__ float s_phys[NPB * 3];
    __shared__ __align__(16) float s_h1[NPB * HH];   // 8 KB
    __shared__ float s_red[4][NPB][2];
    __shared__ float s_kxw[NPB][2];

    if (j < NPB * 3) s_phys[j] = phys[n0 * 3 + j];
    __syncthreads();

    // layer 1
    const float w1v0 = w1[j], w1v1 = w1[HH + j], w1v2 = w1[2 * HH + j], b1v = b1[j];
#pragma unroll
    for (int m = 0; m < NPB; ++m) {
        float h = s_phys[m*3+0] * w1v0 + s_phys[m*3+1] * w1v1 + s_phys[m*3+2] * w1v2 + b1v;
        s_h1[m * HH + j] = fmaxf(h, 0.0f);
    }
    __syncthreads();

    // layer 2
    float acc[NPB];
#pragma unroll
    for (int m = 0; m < NPB; ++m) acc[m] = 0.0f;
#pragma unroll 4
    for (int i4 = 0; i4 < HH / 4; ++i4) {
        const int i = i4 * 4;
        const float wv0 = w2[(i + 0) * HH + j];
        const float wv1 = w2[(i + 1) * HH + j];
        const float wv2 = w2[(i + 2) * HH + j];
        const float wv3 = w2[(i + 3) * HH + j];
#pragma unroll
        for (int m = 0; m < NPB; ++m) {
            const float4 h4 = *(const float4*)&s_h1[m * HH + i];
            acc[m] += h4.x * wv0 + h4.y * wv1 + h4.z * wv2 + h4.w * wv3;
        }
    }

    const float b2v = b2[j];
    const float w30 = w3[j * 2 + 0], w31 = w3[j * 2 + 1];
    const int wv = j >> 6;

#pragma unroll
    for (int m = 0; m < NPB; ++m) {
        const float h2 = fmaxf(acc[m] + b2v, 0.0f);
        float r0 = h2 * w30;
        float r1 = h2 * w31;
#pragma unroll
        for (int o = 32; o >= 1; o >>= 1) {
            r0 += __shfl_xor(r0, o);
            r1 += __shfl_xor(r1, o);
        }
        if ((j & 63) == 0) { s_red[wv][m][0] = r0; s_red[wv][m][1] = r1; }
    }
    __syncthreads();

    if (j < NPB * 2) {
        const int m = j >> 1, d = j & 1;
        float raw = s_red[0][m][d] + s_red[1][m][d] + s_red[2][m][d] + s_red[3][m][d] + b3[d];
        float p;
        if (d == 0) p = sigmoidf_(raw) * 0.25f + 0.005f;          // k
        else        p = sigmoidf_(raw - 3.0f) * 1.2f;             // xw
        s_kxw[m][d] = p;
    }
    __syncthreads();

    // IRF tail: node m = j>>5 (32 lanes/node), taps l and l+32
    {
        const int m = j >> 5, l = j & 31;
        const float k  = s_kxw[m][0];
        const float xw = s_kxw[m][1];
        const float delay = k * xw;
        const float tau   = fmaxf(k * (1.0f - xw), 0.5f * DTF);
        const float t0f = l * DTF, t1f = (l + 32) * DTF;
        float h0 = (t0f >= delay) ? __expf(-(t0f - delay) / tau) / tau : 0.0f;
        float h1 = (t1f >= delay) ? __expf(-(t1f - delay) / tau) / tau : 0.0f;
        float s = h0 + h1;
#pragma unroll
        for (int o = 16; o >= 1; o >>= 1) s += __shfl_xor(s, o);   // stays in 32-lane group
        const float inv = 1.0f / (s + 1e-8f);
        float* dst = irf + (size_t)(n0 + m) * WW;
        dst[l]      = h0 * inv;
        dst[l + 32] = h1 * inv;
    }
}

// ---------------- routing conv: 1 wave/block, OT outputs/thread ----------------
// out[n] = irf_n (x) (x[n] + sum_children out[c]); children of n: 4n+1..4n+4.
// Each thread owns OT consecutive outputs; A-window staged once in LDS.
// reads/output = (OT+64)/4/OT b128 (OT=16: 1.25 vs 4.25 at OT=4).
template<int OT>
__global__ __launch_bounds__(64) void route_conv(
    const float* __restrict__ x,
    const float* __restrict__ irf,
    float* __restrict__ out,
    int level_start)
{
    constexpr int SEG  = 64 * OT;      // outputs per block
    constexpr int NSEG = TT / SEG;     // chunks per row
    const int bid = blockIdx.x;
    const int seg = bid % NSEG;
    const int b   = (bid / NSEG) & 1;
    const int n   = level_start + bid / (NSEG * 2);
    const int tid = threadIdx.x;

    __shared__ __align__(16) float s_acc[SEG + WW];   // s_acc[p] = A(t0-64+p)

    const size_t rowb = ((size_t)b * NN + n) * TT;
    const int t0 = seg * SEG;
    const int c0 = 4 * n + 1;
    const bool hasc = (c0 < NN);

    // stage A window (x + children outs), zeros for t<0
    for (int p = tid; p < (SEG + WW) / 4; p += 64) {
        const int g = t0 - WW + 4 * p;
        float4 v = make_float4(0.f, 0.f, 0.f, 0.f);
        if (g >= 0) {
            v = *(const float4*)&x[rowb + g];
            if (hasc) {
#pragma unroll
                for (int e = 0; e < 4; ++e) {
                    const int c = c0 + e;
                    if (c < NN) {   // node 2047: child 8192 is OOB
                        const float4 u = *(const float4*)&out[((size_t)b * NN + c) * TT + g];
                        v.x += u.x; v.y += u.y; v.z += u.z; v.w += u.w;
                    }
                }
            }
        }
        *(float4*)&s_acc[4 * p] = v;
    }

    // rf via wave-uniform addresses -> scalar loads (SGPRs, off the LDS pipe)
    float rf[WW];
    const float* irp = irf + (size_t)n * WW;
#pragma unroll
    for (int i = 0; i < WW / 4; ++i) {
        const float4 f = *(const float4*)&irp[4 * i];
        rf[4*i+0] = f.x; rf[4*i+1] = f.y; rf[4*i+2] = f.z; rf[4*i+3] = f.w;
    }

    __syncthreads();

    // conv: thread's outputs t0+tid*OT .. +OT-1; window s_acc[tid*OT .. tid*OT+OT+63]
    const int loc = tid * OT;
    float y[OT];
#pragma unroll
    for (int j = 0; j < OT; ++j) y[j] = 0.f;

#pragma unroll
    for (int i = 0; i < (OT + WW) / 4; ++i) {
        const float4 a4 = *(const float4*)&s_acc[loc + 4 * i];
        const float ae[4] = {a4.x, a4.y, a4.z, a4.w};
#pragma unroll
        for (int e = 0; e < 4; ++e) {
            const int pos = 4 * i + e;            // A(base-64+pos)
#pragma unroll
            for (int j = 0; j < OT; ++j) {
                const int w = j + WW - pos;       // tap index, static
                if (w >= 0 && w < WW) y[j] += rf[w] * ae[e];
            }
        }
    }

#pragma unroll
    for (int j4 = 0; j4 < OT / 4; ++j4)
        *(float4*)&out[rowb + t0 + loc + 4 * j4] =
            make_float4(y[4*j4+0], y[4*j4+1], y[4*j4+2], y[4*j4+3]);
}

extern "C" void kernel_launch(void* const* d_in, const int* in_sizes, int n_in,
                              void* d_out, int out_size, void* d_ws, size_t ws_size,
                              hipStream_t stream) {
    const float* x    = (const float*)d_in[0];
    const float* phys = (const float*)d_in[1];
    const float* w1   = (const float*)d_in[2];
    const float* b1   = (const float*)d_in[3];
    const float* w2   = (const float*)d_in[4];
    const float* b2   = (const float*)d_in[5];
    const float* w3   = (const float*)d_in[6];
    const float* b3   = (const float*)d_in[7];
    // d_in[8] = parent, d_in[9] = depth: fixed 4-ary heap tree

    float* out = (float*)d_out;
    float* irf = (float*)d_ws;   // N*64 floats = 2 MB

    mlp_kernel<<<NN / NPB, 256, 0, stream>>>(phys, w1, b1, w2, b2, w3, b3, irf);

    static const int starts[9] = {0, 1, 5, 21, 85, 341, 1365, 5461, 8192};
    for (int d = 7; d >= 0; --d) {
        const int s   = starts[d];
        const int cnt = starts[d + 1] - s;
        if (cnt >= 1024) {
            // big levels: one wave per full row, 16 outputs/thread
            route_conv<16><<<cnt * 2, 64, 0, stream>>>(x, irf, out, s);
        } else {
            // small levels: 4 chunks/row for block count, 4 outputs/thread
            route_conv<4><<<cnt * 2 * 4, 64, 0, stream>>>(x, irf, out, s);
        }
    }
}

// Round 6
// 137.163 us; speedup vs baseline: 1.1519x; 1.1519x over previous
//
#include <hip/hip_runtime.h>

#define NN 8192
#define TT 1024
#define WW 64
#define HH 256
#define NPB 8
#define DTF (1.0f/24.0f)

__device__ __forceinline__ float sigmoidf_(float v) { return 1.0f / (1.0f + __expf(-v)); }

// ---------------- MLP -> (k, xw) -> IRF[n][64] in ws ----------------
__global__ __launch_bounds__(256) void mlp_kernel(
    const float* __restrict__ phys,
    const float* __restrict__ w1, const float* __restrict__ b1,
    const float* __restrict__ w2, const float* __restrict__ b2,
    const float* __restrict__ w3, const float* __restrict__ b3,
    float* __restrict__ irf)
{
    const int n0 = blockIdx.x * NPB;
    const int j  = threadIdx.x;

    __shared__ float s_phys[NPB * 3];
    __shared__ __align__(16) float s_h1[NPB * HH];   // 8 KB
    __shared__ float s_red[4][NPB][2];
    __shared__ float s_kxw[NPB][2];

    if (j < NPB * 3) s_phys[j] = phys[n0 * 3 + j];
    __syncthreads();

    // layer 1
    const float w1v0 = w1[j], w1v1 = w1[HH + j], w1v2 = w1[2 * HH + j], b1v = b1[j];
#pragma unroll
    for (int m = 0; m < NPB; ++m) {
        float h = s_phys[m*3+0] * w1v0 + s_phys[m*3+1] * w1v1 + s_phys[m*3+2] * w1v2 + b1v;
        s_h1[m * HH + j] = fmaxf(h, 0.0f);
    }
    __syncthreads();

    // layer 2
    float acc[NPB];
#pragma unroll
    for (int m = 0; m < NPB; ++m) acc[m] = 0.0f;
#pragma unroll 4
    for (int i4 = 0; i4 < HH / 4; ++i4) {
        const int i = i4 * 4;
        const float wv0 = w2[(i + 0) * HH + j];
        const float wv1 = w2[(i + 1) * HH + j];
        const float wv2 = w2[(i + 2) * HH + j];
        const float wv3 = w2[(i + 3) * HH + j];
#pragma unroll
        for (int m = 0; m < NPB; ++m) {
            const float4 h4 = *(const float4*)&s_h1[m * HH + i];
            acc[m] += h4.x * wv0 + h4.y * wv1 + h4.z * wv2 + h4.w * wv3;
        }
    }

    const float b2v = b2[j];
    const float w30 = w3[j * 2 + 0], w31 = w3[j * 2 + 1];
    const int wv = j >> 6;

#pragma unroll
    for (int m = 0; m < NPB; ++m) {
        const float h2 = fmaxf(acc[m] + b2v, 0.0f);
        float r0 = h2 * w30;
        float r1 = h2 * w31;
#pragma unroll
        for (int o = 32; o >= 1; o >>= 1) {
            r0 += __shfl_xor(r0, o);
            r1 += __shfl_xor(r1, o);
        }
        if ((j & 63) == 0) { s_red[wv][m][0] = r0; s_red[wv][m][1] = r1; }
    }
    __syncthreads();

    if (j < NPB * 2) {
        const int m = j >> 1, d = j & 1;
        float raw = s_red[0][m][d] + s_red[1][m][d] + s_red[2][m][d] + s_red[3][m][d] + b3[d];
        float p;
        if (d == 0) p = sigmoidf_(raw) * 0.25f + 0.005f;          // k
        else        p = sigmoidf_(raw - 3.0f) * 1.2f;             // xw
        s_kxw[m][d] = p;
    }
    __syncthreads();

    // IRF tail: node m = j>>5 (32 lanes/node), taps l and l+32
    {
        const int m = j >> 5, l = j & 31;
        const float k  = s_kxw[m][0];
        const float xw = s_kxw[m][1];
        const float delay = k * xw;
        const float tau   = fmaxf(k * (1.0f - xw), 0.5f * DTF);
        const float t0f = l * DTF, t1f = (l + 32) * DTF;
        float h0 = (t0f >= delay) ? __expf(-(t0f - delay) / tau) / tau : 0.0f;
        float h1 = (t1f >= delay) ? __expf(-(t1f - delay) / tau) / tau : 0.0f;
        float s = h0 + h1;
#pragma unroll
        for (int o = 16; o >= 1; o >>= 1) s += __shfl_xor(s, o);   // stays in 32-lane group
        const float inv = 1.0f / (s + 1e-8f);
        float* dst = irf + (size_t)(n0 + m) * WW;
        dst[l]      = h0 * inv;
        dst[l + 32] = h1 * inv;
    }
}

// ---------------- routing conv: register window + lane shuffles, NO LDS ----------------
// out[n] = irf_n (x) (x[n] + sum_children out[c]); children of n: 4n+1..4n+4.
// One wave per (row, segment); thread owns OT consecutive outputs in registers.
// Halo (64 floats) comes from the NH=64/OT preceding lanes via __shfl (ds_bpermute,
// conflict-free) — d>tid lanes take 0 (seg==0) or a per-lane staged halo float (seg>0).
template<int OT>
__global__ __launch_bounds__(256) void route_shfl(
    const float* __restrict__ x,
    const float* __restrict__ irf,
    float* __restrict__ out,
    int level_start, int n_tasks)
{
    constexpr int SEG  = 64 * OT;
    constexpr int NSEG = TT / SEG;
    constexpr int NH   = WW / OT;      // halo rounds

    const int wid = threadIdx.x >> 6;
    const int tid = threadIdx.x & 63;
    const int r   = blockIdx.x * 4 + wid;
    if (r >= n_tasks) return;          // wave-uniform exit; no barriers in kernel

    const int seg = (NSEG > 1) ? (r % NSEG) : 0;
    const int rb  = (NSEG > 1) ? (r / NSEG) : r;
    const int b   = rb & 1;
    const int n   = __builtin_amdgcn_readfirstlane(level_start + (rb >> 1));
    const size_t rowb = ((size_t)b * NN + n) * TT;
    const int t0  = seg * SEG;
    const int c0  = 4 * n + 1;
    const bool hasc = (c0 < NN);       // leaves (n>=2048) skip child loads entirely

    // stage own chunk a[OT] = A[t0 + tid*OT ...]
    const int loc = t0 + tid * OT;
    float a[OT];
#pragma unroll
    for (int u = 0; u < OT / 4; ++u) {
        float4 v = *(const float4*)&x[rowb + loc + 4 * u];
        if (hasc) {
#pragma unroll
            for (int e = 0; e < 4; ++e) {
                const int c = c0 + e;
                if (c < NN) {          // node 2047: child 8192 is OOB
                    const float4 w = *(const float4*)&out[((size_t)b * NN + c) * TT + loc + 4 * u];
                    v.x += w.x; v.y += w.y; v.z += w.z; v.w += w.w;
                }
            }
        }
        a[4*u+0] = v.x; a[4*u+1] = v.y; a[4*u+2] = v.z; a[4*u+3] = v.w;
    }

    // previous-segment halo: one float per lane, A[t0 - 64 + tid] (only if seg>0)
    float hbv = 0.0f;
    if (NSEG > 1 && seg > 0) {
        const int g = t0 - WW + tid;
        hbv = x[rowb + g];
        if (hasc) {
#pragma unroll
            for (int e = 0; e < 4; ++e) {
                const int c = c0 + e;
                if (c < NN) hbv += out[((size_t)b * NN + c) * TT + g];
            }
        }
    }

    // rf: wave-uniform -> s_load into SGPRs
    float rf[WW];
    const float* irp = irf + (size_t)n * WW;
#pragma unroll
    for (int i = 0; i < WW / 4; ++i) {
        const float4 f = *(const float4*)&irp[4 * i];
        rf[4*i+0] = f.x; rf[4*i+1] = f.y; rf[4*i+2] = f.z; rf[4*i+3] = f.w;
    }

    float y[OT];
#pragma unroll
    for (int j = 0; j < OT; ++j) y[j] = 0.0f;

    // d = 0: own chunk, w = j - m >= 0
#pragma unroll
    for (int m = 0; m < OT; ++m)
#pragma unroll
        for (int j = m; j < OT; ++j)
            y[j] += rf[j - m] * a[m];

    // d = 1..NH: chunk from lane tid-d
#pragma unroll
    for (int d = 1; d <= NH; ++d) {
        float h[OT];
#pragma unroll
        for (int m = 0; m < OT; ++m) {
            const float ha = __shfl(a[m], tid - d);                       // garbage for tid<d
            float hv;
            if (NSEG > 1) {
                const float hh = __shfl(hbv, (WW + OT * (tid - d) + m) & 63);
                hv = (tid >= d) ? ha : ((seg > 0) ? hh : 0.0f);
            } else {
                hv = (tid >= d) ? ha : 0.0f;
            }
            h[m] = hv;
        }
        if (d < NH) {
#pragma unroll
            for (int m = 0; m < OT; ++m)
#pragma unroll
                for (int j = 0; j < OT; ++j)
                    y[j] += rf[j + OT * d - m] * h[m];
        } else {
            // w = j + 64 - m <= 63  ->  j <= m-1
#pragma unroll
            for (int m = 1; m < OT; ++m)
#pragma unroll
                for (int j = 0; j < m; ++j)
                    y[j] += rf[j + WW - m] * h[m];
        }
    }

#pragma unroll
    for (int j4 = 0; j4 < OT / 4; ++j4)
        *(float4*)&out[rowb + loc + 4 * j4] =
            make_float4(y[4*j4+0], y[4*j4+1], y[4*j4+2], y[4*j4+3]);
}

extern "C" void kernel_launch(void* const* d_in, const int* in_sizes, int n_in,
                              void* d_out, int out_size, void* d_ws, size_t ws_size,
                              hipStream_t stream) {
    const float* x    = (const float*)d_in[0];
    const float* phys = (const float*)d_in[1];
    const float* w1   = (const float*)d_in[2];
    const float* b1   = (const float*)d_in[3];
    const float* w2   = (const float*)d_in[4];
    const float* b2   = (const float*)d_in[5];
    const float* w3   = (const float*)d_in[6];
    const float* b3   = (const float*)d_in[7];
    // d_in[8] = parent, d_in[9] = depth: fixed 4-ary heap tree

    float* out = (float*)d_out;
    float* irf = (float*)d_ws;   // N*64 floats = 2 MB

    mlp_kernel<<<NN / NPB, 256, 0, stream>>>(phys, w1, b1, w2, b2, w3, b3, irf);

    static const int starts[9] = {0, 1, 5, 21, 85, 341, 1365, 5461, 8192};
    for (int d = 7; d >= 0; --d) {
        const int s    = starts[d];
        const int cnt  = starts[d + 1] - s;
        const int rows = cnt * 2;
        if (rows >= 2048) {
            // full row per wave, 16 outputs/thread (levels 5,6,7)
            const int tasks = rows;
            route_shfl<16><<<(tasks + 3) / 4, 256, 0, stream>>>(x, irf, out, s, tasks);
        } else {
            // 4 segments/row for parallelism, 4 outputs/thread (levels 0..4)
            const int tasks = rows * 4;
            route_shfl<4><<<(tasks + 3) / 4, 256, 0, stream>>>(x, irf, out, s, tasks);
        }
    }
}

// Round 7
// 124.309 us; speedup vs baseline: 1.2710x; 1.1034x over previous
//
#include <hip/hip_runtime.h>

#define NN 8192
#define TT 1024
#define WW 64
#define HH 256
#define NPB 8
#define DTF (1.0f/24.0f)

__device__ __forceinline__ float sigmoidf_(float v) { return 1.0f / (1.0f + __expf(-v)); }

// ---------------- MLP -> (k, xw) -> IRF[n][64] in ws ----------------
__global__ __launch_bounds__(256) void mlp_kernel(
    const float* __restrict__ phys,
    const float* __restrict__ w1, const float* __restrict__ b1,
    const float* __restrict__ w2, const float* __restrict__ b2,
    const float* __restrict__ w3, const float* __restrict__ b3,
    float* __restrict__ irf)
{
    const int n0 = blockIdx.x * NPB;
    const int j  = threadIdx.x;

    __shared__ float s_phys[NPB * 3];
    __shared__ __align__(16) float s_h1[NPB * HH];   // 8 KB
    __shared__ float s_red[4][NPB][2];
    __shared__ float s_kxw[NPB][2];

    if (j < NPB * 3) s_phys[j] = phys[n0 * 3 + j];
    __syncthreads();

    // layer 1
    const float w1v0 = w1[j], w1v1 = w1[HH + j], w1v2 = w1[2 * HH + j], b1v = b1[j];
#pragma unroll
    for (int m = 0; m < NPB; ++m) {
        float h = s_phys[m*3+0] * w1v0 + s_phys[m*3+1] * w1v1 + s_phys[m*3+2] * w1v2 + b1v;
        s_h1[m * HH + j] = fmaxf(h, 0.0f);
    }
    __syncthreads();

    // layer 2
    float acc[NPB];
#pragma unroll
    for (int m = 0; m < NPB; ++m) acc[m] = 0.0f;
#pragma unroll 4
    for (int i4 = 0; i4 < HH / 4; ++i4) {
        const int i = i4 * 4;
        const float wv0 = w2[(i + 0) * HH + j];
        const float wv1 = w2[(i + 1) * HH + j];
        const float wv2 = w2[(i + 2) * HH + j];
        const float wv3 = w2[(i + 3) * HH + j];
#pragma unroll
        for (int m = 0; m < NPB; ++m) {
            const float4 h4 = *(const float4*)&s_h1[m * HH + i];
            acc[m] += h4.x * wv0 + h4.y * wv1 + h4.z * wv2 + h4.w * wv3;
        }
    }

    const float b2v = b2[j];
    const float w30 = w3[j * 2 + 0], w31 = w3[j * 2 + 1];
    const int wv = j >> 6;

#pragma unroll
    for (int m = 0; m < NPB; ++m) {
        const float h2 = fmaxf(acc[m] + b2v, 0.0f);
        float r0 = h2 * w30;
        float r1 = h2 * w31;
#pragma unroll
        for (int o = 32; o >= 1; o >>= 1) {
            r0 += __shfl_xor(r0, o);
            r1 += __shfl_xor(r1, o);
        }
        if ((j & 63) == 0) { s_red[wv][m][0] = r0; s_red[wv][m][1] = r1; }
    }
    __syncthreads();

    if (j < NPB * 2) {
        const int m = j >> 1, d = j & 1;
        float raw = s_red[0][m][d] + s_red[1][m][d] + s_red[2][m][d] + s_red[3][m][d] + b3[d];
        float p;
        if (d == 0) p = sigmoidf_(raw) * 0.25f + 0.005f;          // k
        else        p = sigmoidf_(raw - 3.0f) * 1.2f;             // xw
        s_kxw[m][d] = p;
    }
    __syncthreads();

    // IRF tail: node m = j>>5 (32 lanes/node), taps l and l+32
    {
        const int m = j >> 5, l = j & 31;
        const float k  = s_kxw[m][0];
        const float xw = s_kxw[m][1];
        const float delay = k * xw;
        const float tau   = fmaxf(k * (1.0f - xw), 0.5f * DTF);
        const float t0f = l * DTF, t1f = (l + 32) * DTF;
        float h0 = (t0f >= delay) ? __expf(-(t0f - delay) / tau) / tau : 0.0f;
        float h1 = (t1f >= delay) ? __expf(-(t1f - delay) / tau) / tau : 0.0f;
        float s = h0 + h1;
#pragma unroll
        for (int o = 16; o >= 1; o >>= 1) s += __shfl_xor(s, o);   // stays in 32-lane group
        const float inv = 1.0f / (s + 1e-8f);
        float* dst = irf + (size_t)(n0 + m) * WW;
        dst[l]      = h0 * inv;
        dst[l + 32] = h1 * inv;
    }
}

// ---------------- leaf conv: nodes >= 2048 (no children), one wave per row ----------------
// out[n] = irf_n (x) x[n]. 75% of all rows, zero dependencies -> one dispatch.
__global__ __launch_bounds__(256) void route_leaf(
    const float* __restrict__ x,
    const float* __restrict__ irf,
    float* __restrict__ out,
    int n_tasks)
{
    constexpr int OT = 16;
    const int wid = threadIdx.x >> 6;
    const int tid = threadIdx.x & 63;
    const int r   = blockIdx.x * 4 + wid;
    if (r >= n_tasks) return;

    const int b = r & 1;
    const int n = __builtin_amdgcn_readfirstlane(2048 + (r >> 1));
    const size_t rowb = ((size_t)b * NN + n) * TT;

    const int loc = tid * OT;
    float a[OT];
#pragma unroll
    for (int u = 0; u < OT / 4; ++u) {
        const float4 v = *(const float4*)&x[rowb + loc + 4 * u];
        a[4*u+0] = v.x; a[4*u+1] = v.y; a[4*u+2] = v.z; a[4*u+3] = v.w;
    }

    float rf[WW];
    const float* irp = irf + (size_t)n * WW;
#pragma unroll
    for (int i = 0; i < WW / 4; ++i) {
        const float4 f = *(const float4*)&irp[4 * i];
        rf[4*i+0] = f.x; rf[4*i+1] = f.y; rf[4*i+2] = f.z; rf[4*i+3] = f.w;
    }

    float y[OT];
#pragma unroll
    for (int j = 0; j < OT; ++j) y[j] = 0.0f;

#pragma unroll
    for (int m = 0; m < OT; ++m)
#pragma unroll
        for (int j = m; j < OT; ++j)
            y[j] += rf[j - m] * a[m];

#pragma unroll
    for (int d = 1; d <= WW / OT; ++d) {
        float h[OT];
#pragma unroll
        for (int m = 0; m < OT; ++m) {
            const float ha = __shfl(a[m], tid - d);
            h[m] = (tid >= d) ? ha : 0.0f;
        }
        if (d < WW / OT) {
#pragma unroll
            for (int m = 0; m < OT; ++m)
#pragma unroll
                for (int j = 0; j < OT; ++j)
                    y[j] += rf[j + OT * d - m] * h[m];
        } else {
#pragma unroll
            for (int m = 1; m < OT; ++m)
#pragma unroll
                for (int j = 0; j < m; ++j)
                    y[j] += rf[j + WW - m] * h[m];
        }
    }

#pragma unroll
    for (int j4 = 0; j4 < OT / 4; ++j4)
        *(float4*)&out[rowb + loc + 4 * j4] =
            make_float4(y[4*j4+0], y[4*j4+1], y[4*j4+2], y[4*j4+3]);
}

// ---------------- internal-node conv: register window + lane shuffles ----------------
// out[n] = irf_n (x) (x[n] + sum_children out[c]); children 4n+1..4n+4 (node 2047's
// 4th child 8192 is OOB -> per-child check). One wave per (row, segment).
template<int OT>
__global__ __launch_bounds__(256) void route_int(
    const float* __restrict__ x,
    const float* __restrict__ irf,
    float* __restrict__ out,
    int level_start, int n_tasks)
{
    constexpr int SEG  = 64 * OT;
    constexpr int NSEG = TT / SEG;
    constexpr int NH   = WW / OT;

    const int wid = threadIdx.x >> 6;
    const int tid = threadIdx.x & 63;
    const int r   = blockIdx.x * 4 + wid;
    if (r >= n_tasks) return;

    const int seg = (NSEG > 1) ? (r % NSEG) : 0;
    const int rb  = (NSEG > 1) ? (r / NSEG) : r;
    const int b   = rb & 1;
    const int n   = __builtin_amdgcn_readfirstlane(level_start + (rb >> 1));
    const size_t rowb = ((size_t)b * NN + n) * TT;
    const int t0  = seg * SEG;
    const int c0  = 4 * n + 1;

    const int loc = t0 + tid * OT;
    float a[OT];
#pragma unroll
    for (int u = 0; u < OT / 4; ++u) {
        float4 v = *(const float4*)&x[rowb + loc + 4 * u];
#pragma unroll
        for (int e = 0; e < 4; ++e) {
            const int c = c0 + e;
            if (c < NN) {
                const float4 w = *(const float4*)&out[((size_t)b * NN + c) * TT + loc + 4 * u];
                v.x += w.x; v.y += w.y; v.z += w.z; v.w += w.w;
            }
        }
        a[4*u+0] = v.x; a[4*u+1] = v.y; a[4*u+2] = v.z; a[4*u+3] = v.w;
    }

    // previous-segment halo: one float per lane, A[t0 - 64 + tid]
    float hbv = 0.0f;
    if (NSEG > 1 && seg > 0) {
        const int g = t0 - WW + tid;
        hbv = x[rowb + g];
#pragma unroll
        for (int e = 0; e < 4; ++e) {
            const int c = c0 + e;
            if (c < NN) hbv += out[((size_t)b * NN + c) * TT + g];
        }
    }

    float rf[WW];
    const float* irp = irf + (size_t)n * WW;
#pragma unroll
    for (int i = 0; i < WW / 4; ++i) {
        const float4 f = *(const float4*)&irp[4 * i];
        rf[4*i+0] = f.x; rf[4*i+1] = f.y; rf[4*i+2] = f.z; rf[4*i+3] = f.w;
    }

    float y[OT];
#pragma unroll
    for (int j = 0; j < OT; ++j) y[j] = 0.0f;

#pragma unroll
    for (int m = 0; m < OT; ++m)
#pragma unroll
        for (int j = m; j < OT; ++j)
            y[j] += rf[j - m] * a[m];

#pragma unroll
    for (int d = 1; d <= NH; ++d) {
        float h[OT];
#pragma unroll
        for (int m = 0; m < OT; ++m) {
            const float ha = __shfl(a[m], tid - d);
            float hv;
            if (NSEG > 1) {
                const float hh = __shfl(hbv, (WW + OT * (tid - d) + m) & 63);
                hv = (tid >= d) ? ha : ((seg > 0) ? hh : 0.0f);
            } else {
                hv = (tid >= d) ? ha : 0.0f;
            }
            h[m] = hv;
        }
        if (d < NH) {
#pragma unroll
            for (int m = 0; m < OT; ++m)
#pragma unroll
                for (int j = 0; j < OT; ++j)
                    y[j] += rf[j + OT * d - m] * h[m];
        } else {
#pragma unroll
            for (int m = 1; m < OT; ++m)
#pragma unroll
                for (int j = 0; j < m; ++j)
                    y[j] += rf[j + WW - m] * h[m];
        }
    }

#pragma unroll
    for (int j4 = 0; j4 < OT / 4; ++j4)
        *(float4*)&out[rowb + loc + 4 * j4] =
            make_float4(y[4*j4+0], y[4*j4+1], y[4*j4+2], y[4*j4+3]);
}

extern "C" void kernel_launch(void* const* d_in, const int* in_sizes, int n_in,
                              void* d_out, int out_size, void* d_ws, size_t ws_size,
                              hipStream_t stream) {
    const float* x    = (const float*)d_in[0];
    const float* phys = (const float*)d_in[1];
    const float* w1   = (const float*)d_in[2];
    const float* b1   = (const float*)d_in[3];
    const float* w2   = (const float*)d_in[4];
    const float* b2   = (const float*)d_in[5];
    const float* w3   = (const float*)d_in[6];
    const float* b3   = (const float*)d_in[7];
    // d_in[8] = parent, d_in[9] = depth: fixed 4-ary heap tree (children 4n+1..4n+4)

    float* out = (float*)d_out;
    float* irf = (float*)d_ws;   // N*64 floats = 2 MB

    mlp_kernel<<<NN / NPB, 256, 0, stream>>>(phys, w1, b1, w2, b2, w3, b3, irf);

    // 1) all leaves (n >= 2048): 6144 nodes x 2 batches, fully parallel
    {
        const int tasks = 6144 * 2;
        route_leaf<<<(tasks + 3) / 4, 256, 0, stream>>>(x, irf, out, tasks);
    }

    // 2) internal chain, bottom-up. starts/counts of internal nodes per level:
    //    L6: 1365..2047 (683), L5: 341..1364 (1024), L4: 85..340 (256),
    //    L3: 21..84 (64), L2: 5..20 (16), L1: 1..4 (4), L0: 0 (1)
    {
        int tasks;
        tasks = 683 * 2 * 2;   // OT=8, NSEG=2
        route_int<8><<<(tasks + 3) / 4, 256, 0, stream>>>(x, irf, out, 1365, tasks);
        tasks = 1024 * 2 * 2;
        route_int<8><<<(tasks + 3) / 4, 256, 0, stream>>>(x, irf, out, 341, tasks);
        tasks = 256 * 2 * 4;   // OT=4, NSEG=4
        route_int<4><<<(tasks + 3) / 4, 256, 0, stream>>>(x, irf, out, 85, tasks);
        tasks = 64 * 2 * 4;
        route_int<4><<<(tasks + 3) / 4, 256, 0, stream>>>(x, irf, out, 21, tasks);
        tasks = 16 * 2 * 4;
        route_int<4><<<(tasks + 3) / 4, 256, 0, stream>>>(x, irf, out, 5, tasks);
        tasks = 4 * 2 * 4;
        route_int<4><<<(tasks + 3) / 4, 256, 0, stream>>>(x, irf, out, 1, tasks);
        tasks = 1 * 2 * 4;
        route_int<4><<<(tasks + 3) / 4, 256, 0, stream>>>(x, irf, out, 0, tasks);
    }
}